// Round 1
// baseline (149.439 us; speedup 1.0000x reference)
//
#include <hip/hip_runtime.h>

#define S_LEN 2048
#define BATCH 4
#define DMODEL 512
#define NHEAD 8
#define HDIM 64
#define ROWS (BATCH * S_LEN) /* 8192 */

using short8 = __attribute__((ext_vector_type(8))) short;
using f32x4  = __attribute__((ext_vector_type(4))) float;

__device__ __forceinline__ unsigned short f2bf(float f) {
  unsigned int u = __builtin_bit_cast(unsigned int, f);
  u += 0x7fffu + ((u >> 16) & 1u);
  return (unsigned short)(u >> 16);
}
__device__ __forceinline__ float bf2f(unsigned short h) {
  unsigned int u = ((unsigned int)h) << 16;
  return __builtin_bit_cast(float, u);
}
__device__ __forceinline__ void glds16(const void* g, void* l) {
  __builtin_amdgcn_global_load_lds((const __attribute__((address_space(1))) unsigned*)g,
                                   (__attribute__((address_space(3))) unsigned*)l, 16, 0, 0);
}

// ========== K1: prep = cvt (0..2047) + transposes (2048..3071) + xsum partials ====
__global__ __launch_bounds__(256) void prep_kernel(const float* __restrict__ x,
                                                   const float* __restrict__ Wq,
                                                   const float* __restrict__ Wk,
                                                   const float* __restrict__ Wv,
                                                   const float* __restrict__ Wo,
                                                   unsigned short* __restrict__ xb,
                                                   unsigned short* __restrict__ WqkT,
                                                   unsigned short* __restrict__ WvT,
                                                   unsigned short* __restrict__ WoT,
                                                   float* __restrict__ xpart) {
  __shared__ float t[32][33];
  const int blk = blockIdx.x, tid = threadIdx.x;
  if (blk < 2048) {
    const int base = (blk * 256 + tid) * 8;
    float4 f0 = *(const float4*)(x + base);
    float4 f1 = *(const float4*)(x + base + 4);
    uint4 o;
    o.x = (unsigned)f2bf(f0.x) | ((unsigned)f2bf(f0.y) << 16);
    o.y = (unsigned)f2bf(f0.z) | ((unsigned)f2bf(f0.w) << 16);
    o.z = (unsigned)f2bf(f1.x) | ((unsigned)f2bf(f1.y) << 16);
    o.w = (unsigned)f2bf(f1.z) | ((unsigned)f2bf(f1.w) << 16);
    *(uint4*)(xb + base) = o;
    return;
  }
  if (blk < 3072) {
    const int tb = blk - 2048;
    const int which = tb >> 8, tile = tb & 255;
    const float* W = which == 0 ? Wq : which == 1 ? Wk : which == 2 ? Wv : Wo;
    unsigned short* WT = which == 0 ? WqkT : which == 1 ? (WqkT + 512 * 512)
                        : which == 2 ? WvT : WoT;
    const int tx = tid & 31, ty = tid >> 5;
    const int x0 = (tile & 15) * 32, y0 = (tile >> 4) * 32;
#pragma unroll
    for (int r = 0; r < 4; r++)
      t[ty + 8 * r][tx] = W[(size_t)(y0 + ty + 8 * r) * DMODEL + x0 + tx];
    __syncthreads();
#pragma unroll
    for (int r = 0; r < 4; r++)
      WT[(size_t)(x0 + ty + 8 * r) * DMODEL + y0 + tx] = f2bf(t[tx][ty + 8 * r]);
    return;
  }
  const int u = blk - 3072; // 64 xsum-partial units
  const int b = u >> 4, cg = (u >> 3) & 1, rc = u & 7;
  const float* base = x + (size_t)(b * S_LEN + rc * 256) * DMODEL + cg * 256 + tid;
  float s = 0.f;
  for (int j = 0; j < 256; j++) s += base[(size_t)j * DMODEL];
  xpart[u * 256 + tid] = s;
}

// ========== K2: QKV GEMM, 2-phase dbuf BK=32 (units 0..767) + vsum GEMV (768..895) =
// T3-minimum pipeline: issue next K-slab's global_load_lds BEFORE the current slab's
// ds_read+MFMA; single vmcnt(0)+barrier per slab. 32KB LDS total -> 3 blocks/CU so
// all 768 GEMM units are co-resident (no tail round).
__global__ __launch_bounds__(256, 3) void qkv_kernel(const unsigned short* __restrict__ xb,
                                                     const unsigned short* __restrict__ WqkT,
                                                     const unsigned short* __restrict__ WvT,
                                                     const float* __restrict__ bq,
                                                     const float* __restrict__ bk,
                                                     const float* __restrict__ bv,
                                                     const int* __restrict__ x_len,
                                                     const float* __restrict__ xpart,
                                                     unsigned short* __restrict__ Qb,
                                                     unsigned short* __restrict__ Kb,
                                                     unsigned short* __restrict__ Vt,
                                                     float* __restrict__ vsum) {
  __shared__ __align__(16) char smem[32768];
  const int bid = blockIdx.x;
  const int tid = threadIdx.x;
  const int wave = tid >> 6, lane = tid & 63;
  if (bid >= 768) {
    // vsum[b][f] = 2048*bv[f] + dot(xsum[b,:], WvT[f,:])  (independent of Vt)
    const int u = bid - 768;
    const int b = u >> 5;
    const int cg = lane >> 5, ko = (lane & 31) * 8;
    float xs[8] = {};
#pragma unroll
    for (int rc = 0; rc < 8; rc++) {
      const float* p = xpart + ((b * 16 + cg * 8 + rc) << 8) + ko;
      float4 a0 = *(const float4*)p;
      float4 a1 = *(const float4*)(p + 4);
      xs[0] += a0.x; xs[1] += a0.y; xs[2] += a0.z; xs[3] += a0.w;
      xs[4] += a1.x; xs[5] += a1.y; xs[6] += a1.z; xs[7] += a1.w;
    }
#pragma unroll
    for (int ci = 0; ci < 4; ci++) {
      const int f = (u & 31) * 16 + wave * 4 + ci;
      const uint4 wv = *(const uint4*)(WvT + (size_t)f * DMODEL + lane * 8);
      const unsigned int w[4] = {wv.x, wv.y, wv.z, wv.w};
      float acc = 0.f;
#pragma unroll
      for (int e = 0; e < 4; e++) {
        acc += xs[2 * e] * bf2f((unsigned short)(w[e] & 0xffffu));
        acc += xs[2 * e + 1] * bf2f((unsigned short)(w[e] >> 16));
      }
#pragma unroll
      for (int off = 1; off < 64; off <<= 1) acc += __shfl_xor(acc, off, 64);
      if (lane == 0) vsum[b * DMODEL + f] = acc + 2048.f * bv[f];
    }
    return;
  }
  const bool vmode = bid < 256;
  const unsigned short *A, *Bt;
  int m0, n0;
  if (vmode) {
    m0 = (bid & 3) * 128;   // feature
    n0 = (bid >> 2) * 128;  // row
    A = WvT; Bt = xb;
    // V rows >= xlen are never observed (p==0 multiplies them; vsum comes from x)
    if ((n0 & 2047) >= x_len[n0 >> 11]) return;
  } else {
    const int q = bid - 256;
    m0 = (q >> 3) * 128;    // row
    n0 = (q & 7) * 128;     // col (0-511 Q, 512-1023 K)
    A = xb; Bt = WqkT;
    const int xl = x_len[m0 >> 11];
    const int s0 = m0 & 2047;
    if (n0 >= DMODEL) { if (s0 >= xl) return; }   // K rows >= xlen unobserved
    else if (s0 >= xl + 128) return;              // Q rows >= xlen+128 unobserved
  }
  const int wr = wave >> 1, wc = wave & 1;
  const int lm = lane & 15, lq = lane >> 4;
  // staging: thread tid stages 16B chunks tid and tid+256 of each 128x32 K-slab.
  // phys chunk (tid&3) at row r holds logical chunk (tid&3) ^ ((r>>1)&3)
  // -> ds_read granules spread 8-distinct per 16-lane group (2-way, free).
  const int r4 = tid >> 2;
  const int cl = (tid & 3) ^ ((tid >> 3) & 3);
  const unsigned short* ga0 = A + (size_t)(m0 + r4) * DMODEL + cl * 8;
  const unsigned short* ga1 = ga0 + (size_t)64 * DMODEL;
  const unsigned short* gb0 = Bt + (size_t)(n0 + r4) * DMODEL + cl * 8;
  const unsigned short* gb1 = gb0 + (size_t)64 * DMODEL;
  char* la0 = smem + tid * 16;          // A buffers at [0,8K),[8K,16K)
  char* lb0 = smem + 16384 + tid * 16;  // B buffers at [16K,24K),[24K,32K)
  // fragment read offsets (bytes within one 8KB K-slab buffer)
  const int phys = (lq ^ ((lm >> 1) & 3)) * 16;
  int aoff[4], boff[4];
#pragma unroll
  for (int mi = 0; mi < 4; mi++) {
    aoff[mi] = (wr * 64 + mi * 16 + lm) * 64 + phys;
    boff[mi] = (wc * 64 + mi * 16 + lm) * 64 + phys;
  }
  f32x4 acc[4][4] = {};
  // prologue: stage slab 0 into buffer 0, drain once
  glds16(ga0, la0);
  glds16(ga1, la0 + 4096);
  glds16(gb0, lb0);
  glds16(gb1, lb0 + 4096);
  __syncthreads();
#pragma unroll
  for (int it = 0; it < 16; ++it) {
    if (it < 15) {  // issue next slab before computing current
      const int nb = ((it + 1) & 1) << 13;
      glds16(ga0 + (it + 1) * 32, la0 + nb);
      glds16(ga1 + (it + 1) * 32, la0 + nb + 4096);
      glds16(gb0 + (it + 1) * 32, lb0 + nb);
      glds16(gb1 + (it + 1) * 32, lb0 + nb + 4096);
    }
    const int ab = (it & 1) << 13;
    short8 af[4], bfr[4];
#pragma unroll
    for (int mi = 0; mi < 4; mi++) af[mi] = *(const short8*)(smem + ab + aoff[mi]);
#pragma unroll
    for (int ni = 0; ni < 4; ni++) bfr[ni] = *(const short8*)(smem + 16384 + ab + boff[ni]);
#pragma unroll
    for (int mi = 0; mi < 4; mi++)
#pragma unroll
      for (int ni = 0; ni < 4; ni++)
        acc[mi][ni] = __builtin_amdgcn_mfma_f32_16x16x32_bf16(af[mi], bfr[ni], acc[mi][ni], 0, 0, 0);
    if (it < 15) __syncthreads();  // single vmcnt(0)+barrier per slab
  }
#pragma unroll
  for (int mi = 0; mi < 4; mi++) {
    const int row0 = m0 + wr * 64 + mi * 16 + lq * 4;
#pragma unroll
    for (int ni = 0; ni < 4; ni++) {
      const int col = n0 + wc * 64 + ni * 16 + lm;
#pragma unroll
      for (int r = 0; r < 4; r++) {
        const int row = row0 + r;
        const float v = acc[mi][ni][r];
        if (vmode) {
          Vt[(size_t)row * ROWS + col] = f2bf(v + bv[row]);
        } else if (col < DMODEL) {
          Qb[(size_t)row * DMODEL + col] = f2bf(v + bq[col]);
        } else {
          Kb[(size_t)row * DMODEL + (col - DMODEL)] = f2bf(v + bk[col - DMODEL]);
        }
      }
    }
  }
}

// ========== K3: banded attention, 64-key tiles (units 0..1023) + tailrow ==========
// T14 pipeline: K/V tiles double-buffered in LDS; next tile's global loads issued to
// registers before compute, ds_write after compute, ONE barrier per tile.
__global__ __launch_bounds__(256) void attn_kernel(const unsigned short* __restrict__ Q,
                                                   const unsigned short* __restrict__ K,
                                                   const unsigned short* __restrict__ Vt,
                                                   const int* __restrict__ x_len,
                                                   const float* __restrict__ vsum,
                                                   const unsigned short* __restrict__ WoT,
                                                   const float* __restrict__ bo,
                                                   float* __restrict__ trow,
                                                   unsigned short* __restrict__ ctx) {
  __shared__ unsigned short Ks[2][64][72];  // 64 keys x 64 dims (+pad), double-buffered
  __shared__ unsigned short Vs[2][64][72];  // 64 dims x 64 keys (+pad), double-buffered
  __shared__ unsigned short Ps[4][16][72];  // per-wave P roundtrip (C->A layout)
  const int tid = threadIdx.x;
  const int unit = blockIdx.x;
  const int wave = tid >> 6, lane = tid & 63;
  if (unit >= 1024) {
    // tailrow: trow[b][c] = bo[c] + (vsum[b]/2048) . WoT[c]
    const int u = unit - 1024;
    const int b = u >> 4;
    const float* vs = vsum + b * DMODEL + lane * 8;
    float vreg[8];
    *(float4*)vreg = *(const float4*)vs;
    *(float4*)(vreg + 4) = *(const float4*)(vs + 4);
#pragma unroll
    for (int ci = 0; ci < 8; ci++) {
      const int c = (u & 15) * 32 + wave * 8 + ci;
      const uint4 wv = *(const uint4*)(WoT + (size_t)c * DMODEL + lane * 8);
      const unsigned int w[4] = {wv.x, wv.y, wv.z, wv.w};
      float acc = 0.f;
#pragma unroll
      for (int e = 0; e < 4; e++) {
        acc += vreg[2 * e] * bf2f((unsigned short)(w[e] & 0xffffu));
        acc += vreg[2 * e + 1] * bf2f((unsigned short)(w[e] >> 16));
      }
#pragma unroll
      for (int off = 1; off < 64; off <<= 1) acc += __shfl_xor(acc, off, 64);
      if (lane == 0) trow[b * DMODEL + c] = bo[c] + acc * (1.f / 2048.f);
    }
    return;
  }
  const int b = unit >> 8, h = (unit >> 5) & 7;
  const int i0 = (unit & 31) * 64;
  const int xlen = x_len[b];
  const int t0 = min(S_LEN, xlen + 128);
  if ((i0 & ~127) >= t0) return; // whole 128-slab is tail: K4 broadcasts it
  const int lm = lane & 15, lq = lane >> 4;
  const int q0 = i0 + wave * 16;
  const size_t qoff = (size_t)(b * S_LEN + q0 + lm) * DMODEL + h * HDIM + lq * 8;
  const short8 aq0 = *(const short8*)(Q + qoff);
  const short8 aq1 = *(const short8*)(Q + qoff + 32);
  const int sr = tid >> 3, sc = (tid & 7) * 8; // staging: 2 rows/dims per thread
  f32x4 oacc[4] = {};
  float lrow[4] = {0.f, 0.f, 0.f, 0.f};
  // block-uniform active tile range [ktlo, kthi):
  //   skip iff jt0+63 < 0  (kt < ktlo)   or   jt0 >= xlen  (kt >= kthi)
  const int ktlo = (i0 >= 128) ? 0 : ((i0 >= 64) ? 1 : 2);
  const int kthi = min(5, (xlen + 128 - i0 + 63) >> 6);
  if (ktlo < kthi) {
    { // prologue: load + write tile ktlo
      const int jt0 = i0 - 128 + ktlo * 64;
      const int jr0 = min(max(jt0 + sr, 0), S_LEN - 1);
      const int jr1 = min(max(jt0 + sr + 32, 0), S_LEN - 1);
      const int jvc = min(max(jt0 + sc, 0), S_LEN - 8);
      const int p = ktlo & 1;
      *(uint4*)&Ks[p][sr][sc] =
          *(const uint4*)(K + (size_t)(b * S_LEN + jr0) * DMODEL + h * HDIM + sc);
      *(uint4*)&Ks[p][sr + 32][sc] =
          *(const uint4*)(K + (size_t)(b * S_LEN + jr1) * DMODEL + h * HDIM + sc);
      *(uint4*)&Vs[p][sr][sc] =
          *(const uint4*)(Vt + (size_t)(h * HDIM + sr) * ROWS + b * S_LEN + jvc);
      *(uint4*)&Vs[p][sr + 32][sc] =
          *(const uint4*)(Vt + (size_t)(h * HDIM + sr + 32) * ROWS + b * S_LEN + jvc);
    }
    __syncthreads();
    for (int kt = ktlo; kt < kthi; kt++) {
      const int p = kt & 1;
      const int jt0 = i0 - 128 + kt * 64;
      const bool more = (kt + 1 < kthi);
      uint4 nk0, nk1, nv0, nv1;
      if (more) { // issue next tile's loads; latency hidden under compute
        const int njt0 = jt0 + 64;
        const int jr0 = min(max(njt0 + sr, 0), S_LEN - 1);
        const int jr1 = min(max(njt0 + sr + 32, 0), S_LEN - 1);
        const int jvc = min(max(njt0 + sc, 0), S_LEN - 8);
        nk0 = *(const uint4*)(K + (size_t)(b * S_LEN + jr0) * DMODEL + h * HDIM + sc);
        nk1 = *(const uint4*)(K + (size_t)(b * S_LEN + jr1) * DMODEL + h * HDIM + sc);
        nv0 = *(const uint4*)(Vt + (size_t)(h * HDIM + sr) * ROWS + b * S_LEN + jvc);
        nv1 = *(const uint4*)(Vt + (size_t)(h * HDIM + sr + 32) * ROWS + b * S_LEN + jvc);
      }
      f32x4 sv[4];
#pragma unroll
      for (int sub = 0; sub < 4; sub++) {
        const short8 bk0 = *(const short8*)&Ks[p][sub * 16 + lm][lq * 8];
        const short8 bk1 = *(const short8*)&Ks[p][sub * 16 + lm][32 + lq * 8];
        f32x4 s = {};
        s = __builtin_amdgcn_mfma_f32_16x16x32_bf16(aq0, bk0, s, 0, 0, 0);
        s = __builtin_amdgcn_mfma_f32_16x16x32_bf16(aq1, bk1, s, 0, 0, 0);
        sv[sub] = s;
      }
      float pp[4][4];
#pragma unroll
      for (int sub = 0; sub < 4; sub++) {
        const int j = jt0 + sub * 16 + lm;
        const bool jv = (j >= 0) && (j < xlen);
#pragma unroll
        for (int r = 0; r < 4; r++) {
          const int i = q0 + lq * 4 + r;
          const bool ok = jv && (j - i <= 128) && (i - j <= 128);
          const float pv = ok ? __expf(sv[sub][r] * 0.125f) : 0.f;
          pp[sub][r] = pv;
          lrow[r] += pv;
        }
      }
#pragma unroll
      for (int sub = 0; sub < 4; sub++)
#pragma unroll
        for (int r = 0; r < 4; r++)
          Ps[wave][lq * 4 + r][sub * 16 + lm] = f2bf(pp[sub][r]);
      // within-wave DS write->read is in program order: no barrier needed
      const short8 pf0 = *(const short8*)&Ps[wave][lm][lq * 8];
      const short8 pf1 = *(const short8*)&Ps[wave][lm][32 + lq * 8];
#pragma unroll
      for (int dt = 0; dt < 4; dt++) {
        const short8 bv0 = *(const short8*)&Vs[p][dt * 16 + lm][lq * 8];
        const short8 bv1 = *(const short8*)&Vs[p][dt * 16 + lm][32 + lq * 8];
        oacc[dt] = __builtin_amdgcn_mfma_f32_16x16x32_bf16(pf0, bv0, oacc[dt], 0, 0, 0);
        oacc[dt] = __builtin_amdgcn_mfma_f32_16x16x32_bf16(pf1, bv1, oacc[dt], 0, 0, 0);
      }
      if (more) { // write next tile into the other buffer; one barrier per tile
        const int np = p ^ 1;
        *(uint4*)&Ks[np][sr][sc] = nk0;
        *(uint4*)&Ks[np][sr + 32][sc] = nk1;
        *(uint4*)&Vs[np][sr][sc] = nv0;
        *(uint4*)&Vs[np][sr + 32][sc] = nv1;
        __syncthreads();
      }
    }
  }
#pragma unroll
  for (int r = 0; r < 4; r++)
#pragma unroll
    for (int off = 1; off < 16; off <<= 1) lrow[r] += __shfl_xor(lrow[r], off, 64);
#pragma unroll
  for (int r = 0; r < 4; r++) {
    const int i = q0 + lq * 4 + r;
    const size_t obase = (size_t)(b * S_LEN + i) * DMODEL + h * HDIM;
    if (lrow[r] > 0.f) {
      const float inv = 1.f / lrow[r];
#pragma unroll
      for (int dt = 0; dt < 4; dt++)
        ctx[obase + dt * 16 + lm] = f2bf(oacc[dt][r] * inv);
    } else {
      // all keys masked -> reference softmax exactly uniform over ALL 2048 keys
#pragma unroll
      for (int dt = 0; dt < 4; dt++)
        ctx[obase + dt * 16 + lm] =
            f2bf(vsum[(size_t)b * DMODEL + h * HDIM + dt * 16 + lm] * (1.f / 2048.f));
    }
  }
}

// ========== K4: output projection, 2-phase dbuf BK=32; tail slabs broadcast trow ===
__global__ __launch_bounds__(256, 2) void out_kernel(const unsigned short* __restrict__ A,
                                                     const unsigned short* __restrict__ Bt,
                                                     const float* __restrict__ bias,
                                                     const int* __restrict__ x_len,
                                                     const float* __restrict__ trow,
                                                     float* __restrict__ out) {
  __shared__ __align__(16) char smem[32768];
  const int tid = threadIdx.x;
  const int m0 = (blockIdx.x >> 2) * 128, n0 = (blockIdx.x & 3) * 128;
  const int xl = x_len[m0 >> 11];
  if ((m0 & 2047) >= min(S_LEN, xl + 128)) {
    const float4 val = *(const float4*)(trow + (m0 >> 11) * DMODEL + n0 + (tid & 31) * 4);
    float* obase = out + (size_t)m0 * DMODEL + n0 + (tid & 31) * 4;
#pragma unroll
    for (int r = tid >> 5; r < 128; r += 8)
      *(float4*)(obase + (size_t)r * DMODEL) = val;
    return;
  }
  const int wave = tid >> 6, lane = tid & 63;
  const int wr = wave >> 1, wc = wave & 1;
  const int lm = lane & 15, lq = lane >> 4;
  const int r4 = tid >> 2;
  const int cl = (tid & 3) ^ ((tid >> 3) & 3);
  const unsigned short* ga0 = A + (size_t)(m0 + r4) * DMODEL + cl * 8;
  const unsigned short* ga1 = ga0 + (size_t)64 * DMODEL;
  const unsigned short* gb0 = Bt + (size_t)(n0 + r4) * DMODEL + cl * 8;
  const unsigned short* gb1 = gb0 + (size_t)64 * DMODEL;
  char* la0 = smem + tid * 16;
  char* lb0 = smem + 16384 + tid * 16;
  const int phys = (lq ^ ((lm >> 1) & 3)) * 16;
  int aoff[4], boff[4];
#pragma unroll
  for (int mi = 0; mi < 4; mi++) {
    aoff[mi] = (wr * 64 + mi * 16 + lm) * 64 + phys;
    boff[mi] = (wc * 64 + mi * 16 + lm) * 64 + phys;
  }
  f32x4 acc[4][4] = {};
  glds16(ga0, la0);
  glds16(ga1, la0 + 4096);
  glds16(gb0, lb0);
  glds16(gb1, lb0 + 4096);
  __syncthreads();
#pragma unroll
  for (int it = 0; it < 16; ++it) {
    if (it < 15) {
      const int nb = ((it + 1) & 1) << 13;
      glds16(ga0 + (it + 1) * 32, la0 + nb);
      glds16(ga1 + (it + 1) * 32, la0 + nb + 4096);
      glds16(gb0 + (it + 1) * 32, lb0 + nb);
      glds16(gb1 + (it + 1) * 32, lb0 + nb + 4096);
    }
    const int ab = (it & 1) << 13;
    short8 af[4], bfr[4];
#pragma unroll
    for (int mi = 0; mi < 4; mi++) af[mi] = *(const short8*)(smem + ab + aoff[mi]);
#pragma unroll
    for (int ni = 0; ni < 4; ni++) bfr[ni] = *(const short8*)(smem + 16384 + ab + boff[ni]);
#pragma unroll
    for (int mi = 0; mi < 4; mi++)
#pragma unroll
      for (int ni = 0; ni < 4; ni++)
        acc[mi][ni] = __builtin_amdgcn_mfma_f32_16x16x32_bf16(af[mi], bfr[ni], acc[mi][ni], 0, 0, 0);
    if (it < 15) __syncthreads();
  }
#pragma unroll
  for (int mi = 0; mi < 4; mi++) {
    const int row0 = m0 + wr * 64 + mi * 16 + lq * 4;
#pragma unroll
    for (int ni = 0; ni < 4; ni++) {
      const int col = n0 + wc * 64 + ni * 16 + lm;
#pragma unroll
      for (int r = 0; r < 4; r++)
        out[(size_t)(row0 + r) * DMODEL + col] = acc[mi][ni][r] + bias[col];
    }
  }
}

extern "C" void kernel_launch(void* const* d_in, const int* in_sizes, int n_in,
                              void* d_out, int out_size, void* d_ws, size_t ws_size,
                              hipStream_t stream) {
  (void)in_sizes; (void)n_in; (void)out_size; (void)ws_size;
  const float* x  = (const float*)d_in[0];
  const float* Wq = (const float*)d_in[1];
  const float* bq = (const float*)d_in[2];
  const float* Wk = (const float*)d_in[3];
  const float* bk = (const float*)d_in[4];
  const float* Wv = (const float*)d_in[5];
  const float* bv = (const float*)d_in[6];
  const float* Wo = (const float*)d_in[7];
  const float* bo = (const float*)d_in[8];
  const int* x_len = (const int*)d_in[9];

  char* ws = (char*)d_ws;
  const size_t MB = 1024 * 1024;
  unsigned short* xb   = (unsigned short*)(ws + 0 * MB);   // [8192][512]
  unsigned short* Qb   = (unsigned short*)(ws + 8 * MB);   // [8192][512]
  unsigned short* Kb   = (unsigned short*)(ws + 16 * MB);  // [8192][512]
  unsigned short* Vt   = (unsigned short*)(ws + 24 * MB);  // [512][8192]
  unsigned short* Cx   = (unsigned short*)(ws + 32 * MB);  // [8192][512]
  unsigned short* WqkT = (unsigned short*)(ws + 40 * MB);  // [1024][512]: Wq^T | Wk^T
  unsigned short* WvT  = (unsigned short*)(ws + 41 * MB);  // [512][512]
  unsigned short* WoT  = (unsigned short*)(ws + 41 * MB + 512 * 1024);
  float* vsum          = (float*)(ws + 42 * MB);           // [4][512]
  float* trow          = (float*)(ws + 42 * MB + 8192);    // [4][512]
  float* xpart         = (float*)(ws + 43 * MB);           // [64][256]

  prep_kernel<<<3136, 256, 0, stream>>>(x, Wq, Wk, Wv, Wo, xb, WqkT, WvT, WoT, xpart);
  qkv_kernel<<<896, 256, 0, stream>>>(xb, WqkT, WvT, bq, bk, bv, x_len, xpart,
                                      Qb, Kb, Vt, vsum);
  attn_kernel<<<1088, 256, 0, stream>>>(Qb, Kb, Vt, x_len, vsum, WoT, bo, trow, Cx);
  out_kernel<<<256, 256, 0, stream>>>(Cx, WoT, bo, x_len, trow, (float*)d_out);
}